// Round 18
// baseline (804.135 us; speedup 1.0000x reference)
//
#include <hip/hip_runtime.h>

typedef int v4i __attribute__((ext_vector_type(4)));

static constexpr int K_DIM = 4096;
static constexpr int BM = 256, BN = 128, BK = 128;   // BK in bytes (=128 i8)
static constexpr int NT = K_DIM / BK;                 // 32 K-tiles

// ---------------- per-token dynamic quantization ----------------
__global__ __launch_bounds__(256) void quant_kernel(const float* __restrict__ x,
                                                    signed char* __restrict__ xq,
                                                    float* __restrict__ xs) {
    const int token = blockIdx.x;
    const float4* row = (const float4*)(x + (size_t)token * K_DIM);
    const int t = threadIdx.x;
    float4 v[4];
    float m = 0.f;
#pragma unroll
    for (int i = 0; i < 4; ++i) {
        v[i] = row[t * 4 + i];
        m = fmaxf(m, fabsf(v[i].x));
        m = fmaxf(m, fabsf(v[i].y));
        m = fmaxf(m, fabsf(v[i].z));
        m = fmaxf(m, fabsf(v[i].w));
    }
#pragma unroll
    for (int d = 32; d > 0; d >>= 1) m = fmaxf(m, __shfl_xor(m, d));
    __shared__ float red[4];
    if ((t & 63) == 0) red[t >> 6] = m;
    __syncthreads();
    const float am = fmaxf(fmaxf(red[0], red[1]), fmaxf(red[2], red[3]));
    const float s = fmaxf(am, 1e-8f) * (1.0f / 127.0f);
    const float inv = 127.0f / fmaxf(am, 1e-8f);

    int pk[4];
#pragma unroll
    for (int i = 0; i < 4; ++i) {
        int q0 = (int)fminf(127.f, fmaxf(-127.f, rintf(v[i].x * inv)));
        int q1 = (int)fminf(127.f, fmaxf(-127.f, rintf(v[i].y * inv)));
        int q2 = (int)fminf(127.f, fmaxf(-127.f, rintf(v[i].z * inv)));
        int q3 = (int)fminf(127.f, fmaxf(-127.f, rintf(v[i].w * inv)));
        pk[i] = (q0 & 255) | ((q1 & 255) << 8) | ((q2 & 255) << 16) | (q3 << 24);
    }
    ((int4*)(xq + (size_t)token * K_DIM))[t] = make_int4(pk[0], pk[1], pk[2], pk[3]);
    if (t == 0) xs[token] = s;
}

// ---------------- weight repack: int32 -> packed int8 ----------------
__global__ __launch_bounds__(256) void repack_kernel(const int* __restrict__ w32,
                                                     int4* __restrict__ w8,
                                                     int n16) {
    const int idx = blockIdx.x * 256 + threadIdx.x;
    if (idx >= n16) return;
    const int4* src = (const int4*)w32 + (size_t)idx * 4;
    int4 a = src[0], b = src[1], c = src[2], d = src[3];
    int p0 = (a.x & 255) | ((a.y & 255) << 8) | ((a.z & 255) << 16) | (a.w << 24);
    int p1 = (b.x & 255) | ((b.y & 255) << 8) | ((b.z & 255) << 16) | (b.w << 24);
    int p2 = (c.x & 255) | ((c.y & 255) << 8) | ((c.z & 255) << 16) | (c.w << 24);
    int p3 = (d.x & 255) | ((d.y & 255) << 8) | ((d.z & 255) << 16) | (d.w << 24);
    w8[idx] = make_int4(p0, p1, p2, p3);
}

// ---- int8 MFMA GEMM: m201-style phase schedule on 3-buf rotation ----
// tile 256x128, BK=128B, 8 waves (4M x 2N), wave 64x64, acc 64 AGPR.
// LDS: 3 bufs x (A 32KB + B 16KB) = 144 KB -> 1 block/CU, 2 waves/SIMD.
// Per tile: 4 double-barrier phases (ks,nh), each {2 stage issues || ds_reads}
// -> barrier -> lgkmcnt(0) -> setprio -> 8 MFMA -> setprio -> barrier.
// Counted vmcnt(6) once per tile (verifies t+1, staged one full body earlier).
__global__ __launch_bounds__(512, 2) void gemm_kernel(const signed char* __restrict__ xq,
                                                      const signed char* __restrict__ w8,
                                                      const float* __restrict__ xs,
                                                      const float* __restrict__ scale,
                                                      const float* __restrict__ bias,
                                                      float* __restrict__ out,
                                                      int N) {
    __shared__ __align__(16) signed char sA[3 * 32768];   // 3 bufs x 256 rows x 128 B
    __shared__ __align__(16) signed char sB[3 * 16384];   // 3 bufs x 128 rows x 128 B

    const int tid = threadIdx.x;
    const int lane = tid & 63;
    const int wid = tid >> 6;          // 8 waves: 4(M) x 2(N)
    const int wm = wid >> 1;           // 0..3
    const int wn = wid & 1;            // 0..1

    // T1: XCD-aware bijective swizzle (grid = 86 x 32 = 2752, divisible by 8)
    const int nwg = gridDim.x * gridDim.y;
    int flat = blockIdx.y * gridDim.x + blockIdx.x;
    if ((nwg & 7) == 0) flat = (flat & 7) * (nwg >> 3) + (flat >> 3);
    const int by = flat % gridDim.y;          // M fast within chunk -> B panel L2-resident
    const int bx = flat / gridDim.y;
    const int m0 = by * BM;
    const int n0 = bx * BN;

    v4i acc[4][4];
    const v4i vzero = {0, 0, 0, 0};
#pragma unroll
    for (int i = 0; i < 4; ++i)
#pragma unroll
        for (int j = 0; j < 4; ++j) acc[i][j] = vzero;

    // ---- staging sources (R1/R4 silicon-verified involution; LDS dest linear) ----
    // LDS row r (=matrix row), phys slot p holds global 16B-chunk (p ^ (r&7)).
    // One issue = 512 thr x 16 B = 64 rows.
    const int srow = tid >> 3;                         // 0..63
    const int sswz = (((tid & 7) ^ (srow & 7)) << 4);
    const signed char* srcA = xq + ((size_t)m0 + srow) * K_DIM + sswz;
    const signed char* srcB = w8 + ((size_t)n0 + srow) * K_DIM + sswz;

    auto stageA2 = [&](int bufoff, int pair, unsigned int kb) {   // A issues {2p, 2p+1}
#pragma unroll
        for (int i = 0; i < 2; ++i) {
            const int issue = pair * 2 + i;
            __builtin_amdgcn_global_load_lds(
                (const __attribute__((address_space(1))) void*)(srcA + (size_t)issue * 64 * K_DIM + kb),
                (__attribute__((address_space(3))) void*)&sA[bufoff + issue * 8192 + wid * 1024],
                16, 0, 0);
        }
    };
    auto stageB1 = [&](int bufoff, int issue, unsigned int kb) {  // B issue {0 or 1}
        __builtin_amdgcn_global_load_lds(
            (const __attribute__((address_space(1))) void*)(srcB + (size_t)issue * 64 * K_DIM + kb),
            (__attribute__((address_space(3))) void*)&sB[bufoff + issue * 8192 + wid * 1024],
            16, 0, 0);
    };

    // ---- read-side constants (R1/R4 measured-zero-conflict pattern) ----
    const int colx0 = (((lane >> 4)) ^ (lane & 7)) << 4;        // ks=0, slots 0-3
    const int colx1 = ((4 + (lane >> 4)) ^ (lane & 7)) << 4;    // ks=1, slots 4-7
    const int rowA = (wm * 64 + (lane & 15)) * 128;             // + mi*2048
    const int rowB = (wn * 64 + (lane & 15)) * 128;             // + (nh*32 + ni*16)*128

    v4i a_[4], b_[2];

#define RD_A(OA, CX)                                                           \
    _Pragma("unroll") for (int mi = 0; mi < 4; ++mi)                           \
        a_[mi] = *(const v4i*)&sA[(OA) + rowA + mi * 2048 + (CX)];
#define RD_B(OB, NH, CX)                                                       \
    _Pragma("unroll") for (int ni = 0; ni < 2; ++ni)                           \
        b_[ni] = *(const v4i*)&sB[(OB) + rowB + (NH) * 4096 + ni * 2048 + (CX)];
#define MM8(NH)                                                                \
    __builtin_amdgcn_s_setprio(1);                                             \
    _Pragma("unroll") for (int mi = 0; mi < 4; ++mi)                           \
    _Pragma("unroll") for (int ni = 0; ni < 2; ++ni)                           \
        acc[mi][(NH) * 2 + ni] = __builtin_amdgcn_mfma_i32_16x16x64_i8(        \
            a_[mi], b_[ni], acc[mi][(NH) * 2 + ni], 0, 0, 0);                  \
    __builtin_amdgcn_s_setprio(0);

    // Body of tile t. Args: RA/RB = read-buf offsets (buf t%3);
    // SA/SB = stage-buf offsets (buf (t+2)%3); DOSTAGE; KB = (t+2)*BK; VMSTR.
#define BODY(RA, RB, SA, SB, DOSTAGE, KB, VMSTR)                               \
    {                                                                          \
        /* P0: ks0,nh0 : stage A pair 0 */                                     \
        asm volatile("" ::: "memory");                                         \
        if (DOSTAGE) stageA2((SA), 0, (KB));                                   \
        RD_A((RA), colx0);                                                     \
        RD_B((RB), 0, colx0);                                                  \
        __builtin_amdgcn_s_barrier();                                          \
        asm volatile("s_waitcnt lgkmcnt(0)" ::: "memory");                     \
        MM8(0);                                                                \
        __builtin_amdgcn_s_barrier();                                          \
        /* P1: ks0,nh1 : stage A pair 1 (A frags held) */                      \
        asm volatile("" ::: "memory");                                         \
        if (DOSTAGE) stageA2((SA), 1, (KB));                                   \
        RD_B((RB), 1, colx0);                                                  \
        __builtin_amdgcn_s_barrier();                                          \
        asm volatile("s_waitcnt lgkmcnt(0)" ::: "memory");                     \
        MM8(1);                                                                \
        __builtin_amdgcn_s_barrier();                                          \
        /* P2: ks1,nh0 : stage B issue 0 */                                    \
        asm volatile("" ::: "memory");                                         \
        if (DOSTAGE) stageB1((SB), 0, (KB));                                   \
        RD_A((RA), colx1);                                                     \
        RD_B((RB), 0, colx1);                                                  \
        __builtin_amdgcn_s_barrier();                                          \
        asm volatile("s_waitcnt lgkmcnt(0)" ::: "memory");                     \
        MM8(0);                                                                \
        __builtin_amdgcn_s_barrier();                                          \
        /* P3: ks1,nh1 : stage B issue 1; counted vmcnt; publish */            \
        asm volatile("" ::: "memory");                                         \
        if (DOSTAGE) stageB1((SB), 1, (KB));                                   \
        RD_B((RB), 1, colx1);                                                  \
        __builtin_amdgcn_s_barrier();                                          \
        asm volatile("s_waitcnt lgkmcnt(0)" ::: "memory");                     \
        MM8(1);                                                                \
        asm volatile("s_waitcnt vmcnt(" VMSTR ")" ::: "memory");               \
        __builtin_amdgcn_s_barrier();                                          \
    }

    // ---- prologue: stage tiles 0 (buf0) and 1 (buf1); publish tile 0 ----
    stageA2(0, 0, 0); stageA2(0, 1, 0); stageB1(0, 0, 0); stageB1(0, 1, 0);
    stageA2(32768, 0, BK); stageA2(32768, 1, BK); stageB1(16384, 0, BK); stageB1(16384, 1, BK);
    asm volatile("s_waitcnt vmcnt(6)" ::: "memory");   // tile 0's 6 issues landed
    __builtin_amdgcn_s_barrier();

    // ---- main loop: bodies t = 0..29 (10 x 3, static buffer offsets) ----
    // t%3=0: read buf0, stage buf2 ; t%3=1: read buf1, stage buf0 ;
    // t%3=2: read buf2, stage buf1
    unsigned int kb = 2 * BK;   // tile staged at body 0
    for (int it = 0; it < 10; ++it) {
        BODY(0,     0,     65536, 32768, 1, kb,          "6");
        BODY(32768, 16384, 0,     0,     1, kb + BK,     "6");
        BODY(65536, 32768, 32768, 16384, 1, kb + 2 * BK, "6");
        kb += 3 * BK;
    }

    // ---- tail: body 30 (read buf0, no stage, vmcnt(0) verifies tile 31);
    // ----       body 31 (read buf1, no stage, vmcnt(0) no-op)
    BODY(0,     0,     0, 0, 0, 0u, "0");
    BODY(32768, 16384, 0, 0, 0, 0u, "0");
#undef BODY

    // ---- output epilogue: D reg r of lane l -> row (l>>4)*4+r, col l&15 per frag
    const int mrow0 = m0 + wm * 64 + ((lane >> 4) << 2);
    const int ncol0 = n0 + wn * 64 + (lane & 15);
    float xsv[4][4];
#pragma unroll
    for (int mi = 0; mi < 4; ++mi)
#pragma unroll
        for (int r = 0; r < 4; ++r) xsv[mi][r] = xs[mrow0 + mi * 16 + r];

#pragma unroll
    for (int ni = 0; ni < 4; ++ni) {
        const int n = ncol0 + ni * 16;
        const float sc = scale[n];
        const float bs = bias[n];
#pragma unroll
        for (int mi = 0; mi < 4; ++mi) {
#pragma unroll
            for (int r = 0; r < 4; ++r) {
                const int m = mrow0 + mi * 16 + r;
                out[(size_t)m * N + n] = (float)acc[mi][ni][r] * xsv[mi][r] * sc + bs;
            }
        }
    }
}

extern "C" void kernel_launch(void* const* d_in, const int* in_sizes, int n_in,
                              void* d_out, int out_size, void* d_ws, size_t ws_size,
                              hipStream_t stream) {
    const float* x     = (const float*)d_in[0];
    const int*   w32   = (const int*)d_in[1];
    const float* scale = (const float*)d_in[2];
    const float* bias  = (const float*)d_in[3];
    float* out = (float*)d_out;

    const int M = in_sizes[0] / K_DIM;   // 8192
    const int N = in_sizes[2];           // 11008

    char* ws = (char*)d_ws;
    signed char* xq = (signed char*)ws;                                  // M*K
    float* xs = (float*)(ws + (size_t)M * K_DIM);                        // M floats
    signed char* w8 = (signed char*)(ws + (size_t)M * K_DIM + (size_t)M * sizeof(float));  // N*K

    quant_kernel<<<M, 256, 0, stream>>>(x, xq, xs);

    const int n16 = (N * K_DIM) / 16;
    repack_kernel<<<(n16 + 255) / 256, 256, 0, stream>>>(w32, (int4*)w8, n16);

    gemm_kernel<<<dim3(N / BN, M / BM), 512, 0, stream>>>(xq, w8, xs, scale, bias, out, N);
}

// Round 19
// 496.404 us; speedup vs baseline: 1.6199x; 1.6199x over previous
//
#include <hip/hip_runtime.h>

typedef int v4i __attribute__((ext_vector_type(4)));

static constexpr int K_DIM = 4096;
static constexpr int BM = 128, BN = 256, BK = 64;

// ---------------- per-token dynamic quantization ----------------
__global__ __launch_bounds__(256) void quant_kernel(const float* __restrict__ x,
                                                    signed char* __restrict__ xq,
                                                    float* __restrict__ xs) {
    const int token = blockIdx.x;
    const float4* row = (const float4*)(x + (size_t)token * K_DIM);
    const int t = threadIdx.x;
    float4 v[4];
    float m = 0.f;
#pragma unroll
    for (int i = 0; i < 4; ++i) {
        v[i] = row[t * 4 + i];
        m = fmaxf(m, fabsf(v[i].x));
        m = fmaxf(m, fabsf(v[i].y));
        m = fmaxf(m, fabsf(v[i].z));
        m = fmaxf(m, fabsf(v[i].w));
    }
#pragma unroll
    for (int d = 32; d > 0; d >>= 1) m = fmaxf(m, __shfl_xor(m, d));
    __shared__ float red[4];
    if ((t & 63) == 0) red[t >> 6] = m;
    __syncthreads();
    const float am = fmaxf(fmaxf(red[0], red[1]), fmaxf(red[2], red[3]));
    const float s = fmaxf(am, 1e-8f) * (1.0f / 127.0f);
    const float inv = 127.0f / fmaxf(am, 1e-8f);

    int pk[4];
#pragma unroll
    for (int i = 0; i < 4; ++i) {
        int q0 = (int)fminf(127.f, fmaxf(-127.f, rintf(v[i].x * inv)));
        int q1 = (int)fminf(127.f, fmaxf(-127.f, rintf(v[i].y * inv)));
        int q2 = (int)fminf(127.f, fmaxf(-127.f, rintf(v[i].z * inv)));
        int q3 = (int)fminf(127.f, fmaxf(-127.f, rintf(v[i].w * inv)));
        pk[i] = (q0 & 255) | ((q1 & 255) << 8) | ((q2 & 255) << 16) | (q3 << 24);
    }
    ((int4*)(xq + (size_t)token * K_DIM))[t] = make_int4(pk[0], pk[1], pk[2], pk[3]);
    if (t == 0) xs[token] = s;
}

// ---------------- weight repack: int32 -> packed int8 ----------------
__global__ __launch_bounds__(256) void repack_kernel(const int* __restrict__ w32,
                                                     int4* __restrict__ w8,
                                                     int n16) {
    const int idx = blockIdx.x * 256 + threadIdx.x;
    if (idx >= n16) return;
    const int4* src = (const int4*)w32 + (size_t)idx * 4;
    int4 a = src[0], b = src[1], c = src[2], d = src[3];
    int p0 = (a.x & 255) | ((a.y & 255) << 8) | ((a.z & 255) << 16) | (a.w << 24);
    int p1 = (b.x & 255) | ((b.y & 255) << 8) | ((b.z & 255) << 16) | (b.w << 24);
    int p2 = (c.x & 255) | ((c.y & 255) << 8) | ((c.z & 255) << 16) | (c.w << 24);
    int p3 = (d.x & 255) | ((d.y & 255) << 8) | ((d.z & 255) << 16) | (d.w << 24);
    w8[idx] = make_int4(p0, p1, p2, p3);
}

// ---- int8 MFMA GEMM: R17 body (single-barrier 3-buf rotation, counted
// ---- vmcnt(3), silicon-verified zero-conflict layout) + 2-D SUPERTILED grid:
// ---- 4 groups of (43 bx x 16 by) bound A's working set to 8 MB/group so A
// ---- stays L3-resident despite the out-stream; B-panel L2 reuse preserved ----
__global__ __launch_bounds__(512, 4) void gemm_kernel(const signed char* __restrict__ xq,
                                                      const signed char* __restrict__ w8,
                                                      const float* __restrict__ xs,
                                                      const float* __restrict__ scale,
                                                      const float* __restrict__ bias,
                                                      float* __restrict__ out,
                                                      int N) {
    __shared__ __align__(16) signed char sA[3 * 8192];    // 3 bufs x 8 KB
    __shared__ __align__(16) signed char sB[3 * 16384];   // 3 bufs x 16 KB

    const int tid = threadIdx.x;
    const int lane = tid & 63;
    const int wid = tid >> 6;          // 8 waves: 2(M) x 4(N)
    const int wm = wid >> 2;
    const int wn = wid & 3;

    // ---- 2-D supertiled block mapping (GROUP=16 by-rows per group) ----
    // grid = 43 x 64; group = 43 bx x 16 by = 688 blocks (688 % 8 == 0).
    // Within group: bijective XCD swizzle, by-fast (B panel L2-resident);
    // A slice per group = 16 x 0.5 MB = 8 MB -> L3-resident across bx sweep.
    const int GROUP = 16;
    int flat = blockIdx.y * gridDim.x + blockIdx.x;
    const int gsize = gridDim.x * GROUP;              // 688
    const int group = flat / gsize;
    int r = flat % gsize;
    if ((gsize & 7) == 0) r = (r & 7) * (gsize >> 3) + (r >> 3);
    const int bx = r / GROUP;
    const int by = group * GROUP + (r % GROUP);
    const int m0 = by * BM;
    const int n0 = bx * BN;

    v4i acc[4][4];
    const v4i vzero = {0, 0, 0, 0};
#pragma unroll
    for (int i = 0; i < 4; ++i)
#pragma unroll
        for (int j = 0; j < 4; ++j) acc[i][j] = vzero;

    // ---- staging sources (silicon-verified involution; LDS dest linear) ----
    const int srow = tid >> 3;
    const int s = (tid & 7) ^ (srow & 7);
    const signed char* srcA = xq + ((size_t)m0 + srow + (s >> 2) * 64) * K_DIM + (s & 3) * 16;
    const signed char* srcB = w8 + ((size_t)n0 + srow + (s >> 2) * 128) * K_DIM + (s & 3) * 16;

    auto stage = [&](int offA, int offB, unsigned int kb) {   // 3 issues: A, B-lo, B-hi
        __builtin_amdgcn_global_load_lds(
            (const __attribute__((address_space(1))) void*)(srcA + kb),
            (__attribute__((address_space(3))) void*)&sA[offA + wid * 1024], 16, 0, 0);
        __builtin_amdgcn_global_load_lds(
            (const __attribute__((address_space(1))) void*)(srcB + kb),
            (__attribute__((address_space(3))) void*)&sB[offB + wid * 1024], 16, 0, 0);
        __builtin_amdgcn_global_load_lds(
            (const __attribute__((address_space(1))) void*)(srcB + (size_t)64 * K_DIM + kb),
            (__attribute__((address_space(3))) void*)&sB[offB + 8192 + wid * 1024], 16, 0, 0);
    };

    // ---- read-side per-lane constants (silicon-verified zero-conflict) ----
    const int colA = ((wm * 4 + (lane >> 4)) ^ (lane & 7)) << 4;
    const int colB = (((wn >> 1) * 4 + (lane >> 4)) ^ (lane & 7)) << 4;
    const int rowA = (lane & 15) * 128;
    const int rowB = ((wn & 1) * 64 + (lane & 15)) * 128;

#define BODY(ORa, ORb, OSa, OSb, DOSTAGE, KB, VMSTR)                           \
    {                                                                          \
        asm volatile("" ::: "memory");          /* pin after prev barrier */   \
        if (DOSTAGE) stage((OSa), (OSb), (KB));                                \
        v4i a_[4], b_[4];                                                      \
        _Pragma("unroll") for (int mi = 0; mi < 4; ++mi)                       \
            a_[mi] = *(const v4i*)&sA[(ORa) + rowA + mi * 2048 + colA];        \
        _Pragma("unroll") for (int ni = 0; ni < 4; ++ni)                       \
            b_[ni] = *(const v4i*)&sB[(ORb) + rowB + ni * 2048 + colB];        \
        __builtin_amdgcn_s_setprio(1);                                         \
        _Pragma("unroll") for (int mi = 0; mi < 4; ++mi)                       \
            _Pragma("unroll") for (int ni = 0; ni < 4; ++ni)                   \
                acc[mi][ni] = __builtin_amdgcn_mfma_i32_16x16x64_i8(           \
                    a_[mi], b_[ni], acc[mi][ni], 0, 0, 0);                     \
        __builtin_amdgcn_s_setprio(0);                                         \
        asm volatile("" ::: "memory");          /* pin before barrier */       \
        asm volatile("s_waitcnt vmcnt(" VMSTR ")" ::: "memory");               \
        __builtin_amdgcn_s_barrier();                                          \
    }

    // ---- prologue: stage tiles 0,1 into bufs 0,1; publish tile 0 ----
    stage(0, 0, 0);
    stage(8192, 16384, BK);
    asm volatile("s_waitcnt vmcnt(3)" ::: "memory");   // tile 0 landed
    __builtin_amdgcn_s_barrier();

    // ---- main loop: bodies 0..59 (20 x 3, static offsets) ----
    // body t: reads buf[t%3], stages tile t+2 into buf[(t+2)%3]
    unsigned int kb = 2 * BK;   // byte offset of tile staged at body 0
    for (int it = 0; it < 20; ++it) {
        BODY(0,     0,     16384, 32768, 1, kb,          "3");  // t=3it+0: rd buf0, st buf2
        BODY(8192,  16384, 0,     0,     1, kb + BK,     "3");  // t=3it+1: rd buf1, st buf0
        BODY(16384, 32768, 8192,  16384, 1, kb + 2 * BK, "3");  // t=3it+2: rd buf2, st buf1
        kb += 3 * BK;
    }

    // ---- tail: bodies 60,61 stage tiles 62,63; body 62 vmcnt(0); body 63 pure ----
    BODY(0,     0,     16384, 32768, 1, (unsigned int)(62 * BK), "3");  // body 60
    BODY(8192,  16384, 0,     0,     1, (unsigned int)(63 * BK), "3");  // body 61
    BODY(16384, 32768, 0,     0,     0, 0u,                      "0");  // body 62
    {   // body 63: reads buf0 (tile 63), MFMA only
        asm volatile("" ::: "memory");
        v4i a_[4], b_[4];
#pragma unroll
        for (int mi = 0; mi < 4; ++mi)
            a_[mi] = *(const v4i*)&sA[0 + rowA + mi * 2048 + colA];
#pragma unroll
        for (int ni = 0; ni < 4; ++ni)
            b_[ni] = *(const v4i*)&sB[0 + rowB + ni * 2048 + colB];
        __builtin_amdgcn_s_setprio(1);
#pragma unroll
        for (int mi = 0; mi < 4; ++mi)
#pragma unroll
            for (int ni = 0; ni < 4; ++ni)
                acc[mi][ni] = __builtin_amdgcn_mfma_i32_16x16x64_i8(
                    a_[mi], b_[ni], acc[mi][ni], 0, 0, 0);
        __builtin_amdgcn_s_setprio(0);
    }
#undef BODY

    // ---- output epilogue: D reg r of lane l -> row (l>>4)*4+r, col l&15 per frag
    const int mrow0 = m0 + wm * 64 + ((lane >> 4) << 2);
    const int ncol0 = n0 + wn * 64 + (lane & 15);
    float xsv[4][4];
#pragma unroll
    for (int mi = 0; mi < 4; ++mi)
#pragma unroll
        for (int r2 = 0; r2 < 4; ++r2) xsv[mi][r2] = xs[mrow0 + mi * 16 + r2];

#pragma unroll
    for (int ni = 0; ni < 4; ++ni) {
        const int n = ncol0 + ni * 16;
        const float sc = scale[n];
        const float bs = bias[n];
#pragma unroll
        for (int mi = 0; mi < 4; ++mi) {
#pragma unroll
            for (int r2 = 0; r2 < 4; ++r2) {
                const int m = mrow0 + mi * 16 + r2;
                out[(size_t)m * N + n] = (float)acc[mi][ni][r2] * xsv[mi][r2] * sc + bs;
            }
        }
    }
}

extern "C" void kernel_launch(void* const* d_in, const int* in_sizes, int n_in,
                              void* d_out, int out_size, void* d_ws, size_t ws_size,
                              hipStream_t stream) {
    const float* x     = (const float*)d_in[0];
    const int*   w32   = (const int*)d_in[1];
    const float* scale = (const float*)d_in[2];
    const float* bias  = (const float*)d_in[3];
    float* out = (float*)d_out;

    const int M = in_sizes[0] / K_DIM;   // 8192
    const int N = in_sizes[2];           // 11008

    char* ws = (char*)d_ws;
    signed char* xq = (signed char*)ws;                                  // M*K
    float* xs = (float*)(ws + (size_t)M * K_DIM);                        // M floats
    signed char* w8 = (signed char*)(ws + (size_t)M * K_DIM + (size_t)M * sizeof(float));  // N*K

    quant_kernel<<<M, 256, 0, stream>>>(x, xq, xs);

    const int n16 = (N * K_DIM) / 16;
    repack_kernel<<<(n16 + 255) / 256, 256, 0, stream>>>(w32, (int4*)w8, n16);

    gemm_kernel<<<dim3(N / BN, M / BM), 512, 0, stream>>>(xq, w8, xs, scale, bias, out, N);
}

// Round 20
// 469.320 us; speedup vs baseline: 1.7134x; 1.0577x over previous
//
#include <hip/hip_runtime.h>

typedef int v4i __attribute__((ext_vector_type(4)));

static constexpr int K_DIM = 4096;
static constexpr int BM = 128, BN = 256, BK = 64;

// ---------------- per-token dynamic quantization ----------------
__global__ __launch_bounds__(256) void quant_kernel(const float* __restrict__ x,
                                                    signed char* __restrict__ xq,
                                                    float* __restrict__ xs) {
    const int token = blockIdx.x;
    const float4* row = (const float4*)(x + (size_t)token * K_DIM);
    const int t = threadIdx.x;
    float4 v[4];
    float m = 0.f;
#pragma unroll
    for (int i = 0; i < 4; ++i) {
        v[i] = row[t * 4 + i];
        m = fmaxf(m, fabsf(v[i].x));
        m = fmaxf(m, fabsf(v[i].y));
        m = fmaxf(m, fabsf(v[i].z));
        m = fmaxf(m, fabsf(v[i].w));
    }
#pragma unroll
    for (int d = 32; d > 0; d >>= 1) m = fmaxf(m, __shfl_xor(m, d));
    __shared__ float red[4];
    if ((t & 63) == 0) red[t >> 6] = m;
    __syncthreads();
    const float am = fmaxf(fmaxf(red[0], red[1]), fmaxf(red[2], red[3]));
    const float s = fmaxf(am, 1e-8f) * (1.0f / 127.0f);
    const float inv = 127.0f / fmaxf(am, 1e-8f);

    int pk[4];
#pragma unroll
    for (int i = 0; i < 4; ++i) {
        int q0 = (int)fminf(127.f, fmaxf(-127.f, rintf(v[i].x * inv)));
        int q1 = (int)fminf(127.f, fmaxf(-127.f, rintf(v[i].y * inv)));
        int q2 = (int)fminf(127.f, fmaxf(-127.f, rintf(v[i].z * inv)));
        int q3 = (int)fminf(127.f, fmaxf(-127.f, rintf(v[i].w * inv)));
        pk[i] = (q0 & 255) | ((q1 & 255) << 8) | ((q2 & 255) << 16) | (q3 << 24);
    }
    ((int4*)(xq + (size_t)token * K_DIM))[t] = make_int4(pk[0], pk[1], pk[2], pk[3]);
    if (t == 0) xs[token] = s;
}

// ---------------- weight repack: int32 -> packed int8 ----------------
__global__ __launch_bounds__(256) void repack_kernel(const int* __restrict__ w32,
                                                     int4* __restrict__ w8,
                                                     int n16) {
    const int idx = blockIdx.x * 256 + threadIdx.x;
    if (idx >= n16) return;
    const int4* src = (const int4*)w32 + (size_t)idx * 4;
    int4 a = src[0], b = src[1], c = src[2], d = src[3];
    int p0 = (a.x & 255) | ((a.y & 255) << 8) | ((a.z & 255) << 16) | (a.w << 24);
    int p1 = (b.x & 255) | ((b.y & 255) << 8) | ((b.z & 255) << 16) | (b.w << 24);
    int p2 = (c.x & 255) | ((c.y & 255) << 8) | ((c.z & 255) << 16) | (c.w << 24);
    int p3 = (d.x & 255) | ((d.y & 255) << 8) | ((d.z & 255) << 16) | (d.w << 24);
    w8[idx] = make_int4(p0, p1, p2, p3);
}

// ---- int8 MFMA GEMM: R19 (single-barrier 3-buf rotation, counted vmcnt(3),
// ---- silicon-verified zero-conflict layout, 2-D supertiled grid) +
// ---- LDS-transpose epilogue: float4 stores, 256-B contiguous per 16 lanes
// ---- -> full-cacheline writes, no read-for-ownership HBM fetch of `out` ----
__global__ __launch_bounds__(512, 4) void gemm_kernel(const signed char* __restrict__ xq,
                                                      const signed char* __restrict__ w8,
                                                      const float* __restrict__ xs,
                                                      const float* __restrict__ scale,
                                                      const float* __restrict__ bias,
                                                      float* __restrict__ out,
                                                      int N) {
    __shared__ __align__(16) signed char smem_[73728];   // sA 24 KB | sB 48 KB; reused as epilogue scratch
#define sA (smem_)
#define sB (smem_ + 24576)

    const int tid = threadIdx.x;
    const int lane = tid & 63;
    const int wid = tid >> 6;          // 8 waves: 2(M) x 4(N)
    const int wm = wid >> 2;
    const int wn = wid & 3;

    // ---- 2-D supertiled block mapping (GROUP=16 by-rows per group) ----
    const int GROUP = 16;
    int flat = blockIdx.y * gridDim.x + blockIdx.x;
    const int gsize = gridDim.x * GROUP;              // 688
    const int group = flat / gsize;
    int r = flat % gsize;
    if ((gsize & 7) == 0) r = (r & 7) * (gsize >> 3) + (r >> 3);
    const int bx = r / GROUP;
    const int by = group * GROUP + (r % GROUP);
    const int m0 = by * BM;
    const int n0 = bx * BN;

    v4i acc[4][4];
    const v4i vzero = {0, 0, 0, 0};
#pragma unroll
    for (int i = 0; i < 4; ++i)
#pragma unroll
        for (int j = 0; j < 4; ++j) acc[i][j] = vzero;

    // ---- staging sources (silicon-verified involution; LDS dest linear) ----
    const int srow = tid >> 3;
    const int s = (tid & 7) ^ (srow & 7);
    const signed char* srcA = xq + ((size_t)m0 + srow + (s >> 2) * 64) * K_DIM + (s & 3) * 16;
    const signed char* srcB = w8 + ((size_t)n0 + srow + (s >> 2) * 128) * K_DIM + (s & 3) * 16;

    auto stage = [&](int offA, int offB, unsigned int kb) {   // 3 issues: A, B-lo, B-hi
        __builtin_amdgcn_global_load_lds(
            (const __attribute__((address_space(1))) void*)(srcA + kb),
            (__attribute__((address_space(3))) void*)&sA[offA + wid * 1024], 16, 0, 0);
        __builtin_amdgcn_global_load_lds(
            (const __attribute__((address_space(1))) void*)(srcB + kb),
            (__attribute__((address_space(3))) void*)&sB[offB + wid * 1024], 16, 0, 0);
        __builtin_amdgcn_global_load_lds(
            (const __attribute__((address_space(1))) void*)(srcB + (size_t)64 * K_DIM + kb),
            (__attribute__((address_space(3))) void*)&sB[offB + 8192 + wid * 1024], 16, 0, 0);
    };

    // ---- read-side per-lane constants (silicon-verified zero-conflict) ----
    const int colA = ((wm * 4 + (lane >> 4)) ^ (lane & 7)) << 4;
    const int colB = (((wn >> 1) * 4 + (lane >> 4)) ^ (lane & 7)) << 4;
    const int rowA = (lane & 15) * 128;
    const int rowB = ((wn & 1) * 64 + (lane & 15)) * 128;

#define BODY(ORa, ORb, OSa, OSb, DOSTAGE, KB, VMSTR)                           \
    {                                                                          \
        asm volatile("" ::: "memory");          /* pin after prev barrier */   \
        if (DOSTAGE) stage((OSa), (OSb), (KB));                                \
        v4i a_[4], b_[4];                                                      \
        _Pragma("unroll") for (int mi = 0; mi < 4; ++mi)                       \
            a_[mi] = *(const v4i*)&sA[(ORa) + rowA + mi * 2048 + colA];        \
        _Pragma("unroll") for (int ni = 0; ni < 4; ++ni)                       \
            b_[ni] = *(const v4i*)&sB[(ORb) + rowB + ni * 2048 + colB];        \
        __builtin_amdgcn_s_setprio(1);                                         \
        _Pragma("unroll") for (int mi = 0; mi < 4; ++mi)                       \
            _Pragma("unroll") for (int ni = 0; ni < 4; ++ni)                   \
                acc[mi][ni] = __builtin_amdgcn_mfma_i32_16x16x64_i8(           \
                    a_[mi], b_[ni], acc[mi][ni], 0, 0, 0);                     \
        __builtin_amdgcn_s_setprio(0);                                         \
        asm volatile("" ::: "memory");          /* pin before barrier */       \
        asm volatile("s_waitcnt vmcnt(" VMSTR ")" ::: "memory");               \
        __builtin_amdgcn_s_barrier();                                          \
    }

    // ---- prologue: stage tiles 0,1 into bufs 0,1; publish tile 0 ----
    stage(0, 0, 0);
    stage(8192, 16384, BK);
    asm volatile("s_waitcnt vmcnt(3)" ::: "memory");   // tile 0 landed
    __builtin_amdgcn_s_barrier();

    // ---- main loop: bodies 0..59 (20 x 3, static offsets) ----
    unsigned int kb = 2 * BK;   // byte offset of tile staged at body 0
    for (int it = 0; it < 20; ++it) {
        BODY(0,     0,     16384, 32768, 1, kb,          "3");  // t=3it+0: rd buf0, st buf2
        BODY(8192,  16384, 0,     0,     1, kb + BK,     "3");  // t=3it+1: rd buf1, st buf0
        BODY(16384, 32768, 8192,  16384, 1, kb + 2 * BK, "3");  // t=3it+2: rd buf2, st buf1
        kb += 3 * BK;
    }

    // ---- tail: bodies 60,61 stage tiles 62,63; body 62 vmcnt(0); body 63 pure ----
    BODY(0,     0,     16384, 32768, 1, (unsigned int)(62 * BK), "3");  // body 60
    BODY(8192,  16384, 0,     0,     1, (unsigned int)(63 * BK), "3");  // body 61
    BODY(16384, 32768, 0,     0,     0, 0u,                      "0");  // body 62
    {   // body 63: reads buf0 (tile 63), MFMA only
        asm volatile("" ::: "memory");
        v4i a_[4], b_[4];
#pragma unroll
        for (int mi = 0; mi < 4; ++mi)
            a_[mi] = *(const v4i*)&sA[0 + rowA + mi * 2048 + colA];
#pragma unroll
        for (int ni = 0; ni < 4; ++ni)
            b_[ni] = *(const v4i*)&sB[0 + rowB + ni * 2048 + colB];
        __builtin_amdgcn_s_setprio(1);
#pragma unroll
        for (int mi = 0; mi < 4; ++mi)
#pragma unroll
            for (int ni = 0; ni < 4; ++ni)
                acc[mi][ni] = __builtin_amdgcn_mfma_i32_16x16x64_i8(
                    a_[mi], b_[ni], acc[mi][ni], 0, 0, 0);
        __builtin_amdgcn_s_setprio(0);
    }
#undef BODY

    // ---- LDS-transpose epilogue: full-cacheline float4 stores ----
    // Per-wave scratch: 32 rows x 68 floats (stride-padded) = 8704 B; 8 x 8704 = 69632 <= 73728.
    __syncthreads();   // all LDS reads of the K-loop complete before reuse
    float* ws_ = (float*)&smem_[wid * 8704];

    const int mrow0 = m0 + wm * 64 + ((lane >> 4) << 2);
    const int ncol0 = n0 + wn * 64 + (lane & 15);
    float xsv[4][4], scv[4], bsv[4];
#pragma unroll
    for (int mi = 0; mi < 4; ++mi)
#pragma unroll
        for (int r2 = 0; r2 < 4; ++r2) xsv[mi][r2] = xs[mrow0 + mi * 16 + r2];
#pragma unroll
    for (int ni = 0; ni < 4; ++ni) {
        scv[ni] = scale[ncol0 + ni * 16];
        bsv[ni] = bias[ncol0 + ni * 16];
    }

    const int mbase = m0 + wm * 64;
    const int nbase = n0 + wn * 64;
#pragma unroll
    for (int pass = 0; pass < 2; ++pass) {
        // scale + dump 2 mi-blocks (32 output rows) into scratch
#pragma unroll
        for (int mh = 0; mh < 2; ++mh) {
            const int mi = pass * 2 + mh;
#pragma unroll
            for (int ni = 0; ni < 4; ++ni) {
#pragma unroll
                for (int r2 = 0; r2 < 4; ++r2) {
                    const int lrow = mh * 16 + ((lane >> 4) << 2) + r2;
                    ws_[lrow * 68 + ni * 16 + (lane & 15)] =
                        (float)acc[mi][ni][r2] * xsv[mi][r2] * scv[ni] + bsv[ni];
                }
            }
        }
        // read back row-major + float4 stores: 16 lanes cover one 256-B row segment
#pragma unroll
        for (int j = 0; j < 8; ++j) {
            const int lrow = j * 4 + (lane >> 4);
            const float4 v4 = *(const float4*)&ws_[lrow * 68 + (lane & 15) * 4];
            const int m = mbase + pass * 32 + lrow;
            *(float4*)&out[(size_t)m * N + nbase + (lane & 15) * 4] = v4;
        }
    }
#undef sA
#undef sB
}

extern "C" void kernel_launch(void* const* d_in, const int* in_sizes, int n_in,
                              void* d_out, int out_size, void* d_ws, size_t ws_size,
                              hipStream_t stream) {
    const float* x     = (const float*)d_in[0];
    const int*   w32   = (const int*)d_in[1];
    const float* scale = (const float*)d_in[2];
    const float* bias  = (const float*)d_in[3];
    float* out = (float*)d_out;

    const int M = in_sizes[0] / K_DIM;   // 8192
    const int N = in_sizes[2];           // 11008

    char* ws = (char*)d_ws;
    signed char* xq = (signed char*)ws;                                  // M*K
    float* xs = (float*)(ws + (size_t)M * K_DIM);                        // M floats
    signed char* w8 = (signed char*)(ws + (size_t)M * K_DIM + (size_t)M * sizeof(float));  // N*K

    quant_kernel<<<M, 256, 0, stream>>>(x, xq, xs);

    const int n16 = (N * K_DIM) / 16;
    repack_kernel<<<(n16 + 255) / 256, 256, 0, stream>>>(w32, (int4*)w8, n16);

    gemm_kernel<<<dim3(N / BN, M / BM), 512, 0, stream>>>(xq, w8, xs, scale, bias, out, N);
}

// Round 22
// 458.174 us; speedup vs baseline: 1.7551x; 1.0243x over previous
//
#include <hip/hip_runtime.h>

typedef int v4i __attribute__((ext_vector_type(4)));
typedef float f32x4 __attribute__((ext_vector_type(4)));

static constexpr int K_DIM = 4096;
static constexpr int BM = 128, BN = 256, BK = 64;

// ---------------- per-token dynamic quantization ----------------
__global__ __launch_bounds__(256) void quant_kernel(const float* __restrict__ x,
                                                    signed char* __restrict__ xq,
                                                    float* __restrict__ xs) {
    const int token = blockIdx.x;
    const float4* row = (const float4*)(x + (size_t)token * K_DIM);
    const int t = threadIdx.x;
    float4 v[4];
    float m = 0.f;
#pragma unroll
    for (int i = 0; i < 4; ++i) {
        v[i] = row[t * 4 + i];
        m = fmaxf(m, fabsf(v[i].x));
        m = fmaxf(m, fabsf(v[i].y));
        m = fmaxf(m, fabsf(v[i].z));
        m = fmaxf(m, fabsf(v[i].w));
    }
#pragma unroll
    for (int d = 32; d > 0; d >>= 1) m = fmaxf(m, __shfl_xor(m, d));
    __shared__ float red[4];
    if ((t & 63) == 0) red[t >> 6] = m;
    __syncthreads();
    const float am = fmaxf(fmaxf(red[0], red[1]), fmaxf(red[2], red[3]));
    const float s = fmaxf(am, 1e-8f) * (1.0f / 127.0f);
    const float inv = 127.0f / fmaxf(am, 1e-8f);

    int pk[4];
#pragma unroll
    for (int i = 0; i < 4; ++i) {
        int q0 = (int)fminf(127.f, fmaxf(-127.f, rintf(v[i].x * inv)));
        int q1 = (int)fminf(127.f, fmaxf(-127.f, rintf(v[i].y * inv)));
        int q2 = (int)fminf(127.f, fmaxf(-127.f, rintf(v[i].z * inv)));
        int q3 = (int)fminf(127.f, fmaxf(-127.f, rintf(v[i].w * inv)));
        pk[i] = (q0 & 255) | ((q1 & 255) << 8) | ((q2 & 255) << 16) | (q3 << 24);
    }
    ((int4*)(xq + (size_t)token * K_DIM))[t] = make_int4(pk[0], pk[1], pk[2], pk[3]);
    if (t == 0) xs[token] = s;
}

// ---------------- weight repack: int32 -> packed int8 ----------------
__global__ __launch_bounds__(256) void repack_kernel(const int* __restrict__ w32,
                                                     int4* __restrict__ w8,
                                                     int n16) {
    const int idx = blockIdx.x * 256 + threadIdx.x;
    if (idx >= n16) return;
    const int4* src = (const int4*)w32 + (size_t)idx * 4;
    int4 a = src[0], b = src[1], c = src[2], d = src[3];
    int p0 = (a.x & 255) | ((a.y & 255) << 8) | ((a.z & 255) << 16) | (a.w << 24);
    int p1 = (b.x & 255) | ((b.y & 255) << 8) | ((b.z & 255) << 16) | (b.w << 24);
    int p2 = (c.x & 255) | ((c.y & 255) << 8) | ((c.z & 255) << 16) | (c.w << 24);
    int p3 = (d.x & 255) | ((d.y & 255) << 8) | ((d.z & 255) << 16) | (d.w << 24);
    w8[idx] = make_int4(p0, p1, p2, p3);
}

// ---- int8 MFMA GEMM: R20 (single-barrier 3-buf rotation, counted vmcnt(3),
// ---- silicon-verified zero-conflict layout, 2-D supertiled grid, LDS-transpose
// ---- epilogue) + NON-TEMPORAL out stores (native clang vector type): the
// ---- 360 MB write stream bypasses L2/L3 so A slice/B panels survive cache ----
__global__ __launch_bounds__(512, 4) void gemm_kernel(const signed char* __restrict__ xq,
                                                      const signed char* __restrict__ w8,
                                                      const float* __restrict__ xs,
                                                      const float* __restrict__ scale,
                                                      const float* __restrict__ bias,
                                                      float* __restrict__ out,
                                                      int N) {
    __shared__ __align__(16) signed char smem_[73728];   // sA 24 KB | sB 48 KB; reused as epilogue scratch
#define sA (smem_)
#define sB (smem_ + 24576)

    const int tid = threadIdx.x;
    const int lane = tid & 63;
    const int wid = tid >> 6;          // 8 waves: 2(M) x 4(N)
    const int wm = wid >> 2;
    const int wn = wid & 3;

    // ---- 2-D supertiled block mapping (GROUP=16 by-rows per group) ----
    const int GROUP = 16;
    int flat = blockIdx.y * gridDim.x + blockIdx.x;
    const int gsize = gridDim.x * GROUP;              // 688
    const int group = flat / gsize;
    int r = flat % gsize;
    if ((gsize & 7) == 0) r = (r & 7) * (gsize >> 3) + (r >> 3);
    const int bx = r / GROUP;
    const int by = group * GROUP + (r % GROUP);
    const int m0 = by * BM;
    const int n0 = bx * BN;

    v4i acc[4][4];
    const v4i vzero = {0, 0, 0, 0};
#pragma unroll
    for (int i = 0; i < 4; ++i)
#pragma unroll
        for (int j = 0; j < 4; ++j) acc[i][j] = vzero;

    // ---- staging sources (silicon-verified involution; LDS dest linear) ----
    const int srow = tid >> 3;
    const int s = (tid & 7) ^ (srow & 7);
    const signed char* srcA = xq + ((size_t)m0 + srow + (s >> 2) * 64) * K_DIM + (s & 3) * 16;
    const signed char* srcB = w8 + ((size_t)n0 + srow + (s >> 2) * 128) * K_DIM + (s & 3) * 16;

    auto stage = [&](int offA, int offB, unsigned int kb) {   // 3 issues: A, B-lo, B-hi
        __builtin_amdgcn_global_load_lds(
            (const __attribute__((address_space(1))) void*)(srcA + kb),
            (__attribute__((address_space(3))) void*)&sA[offA + wid * 1024], 16, 0, 0);
        __builtin_amdgcn_global_load_lds(
            (const __attribute__((address_space(1))) void*)(srcB + kb),
            (__attribute__((address_space(3))) void*)&sB[offB + wid * 1024], 16, 0, 0);
        __builtin_amdgcn_global_load_lds(
            (const __attribute__((address_space(1))) void*)(srcB + (size_t)64 * K_DIM + kb),
            (__attribute__((address_space(3))) void*)&sB[offB + 8192 + wid * 1024], 16, 0, 0);
    };

    // ---- read-side per-lane constants (silicon-verified zero-conflict) ----
    const int colA = ((wm * 4 + (lane >> 4)) ^ (lane & 7)) << 4;
    const int colB = (((wn >> 1) * 4 + (lane >> 4)) ^ (lane & 7)) << 4;
    const int rowA = (lane & 15) * 128;
    const int rowB = ((wn & 1) * 64 + (lane & 15)) * 128;

#define BODY(ORa, ORb, OSa, OSb, DOSTAGE, KB, VMSTR)                           \
    {                                                                          \
        asm volatile("" ::: "memory");          /* pin after prev barrier */   \
        if (DOSTAGE) stage((OSa), (OSb), (KB));                                \
        v4i a_[4], b_[4];                                                      \
        _Pragma("unroll") for (int mi = 0; mi < 4; ++mi)                       \
            a_[mi] = *(const v4i*)&sA[(ORa) + rowA + mi * 2048 + colA];        \
        _Pragma("unroll") for (int ni = 0; ni < 4; ++ni)                       \
            b_[ni] = *(const v4i*)&sB[(ORb) + rowB + ni * 2048 + colB];        \
        __builtin_amdgcn_s_setprio(1);                                         \
        _Pragma("unroll") for (int mi = 0; mi < 4; ++mi)                       \
            _Pragma("unroll") for (int ni = 0; ni < 4; ++ni)                   \
                acc[mi][ni] = __builtin_amdgcn_mfma_i32_16x16x64_i8(           \
                    a_[mi], b_[ni], acc[mi][ni], 0, 0, 0);                     \
        __builtin_amdgcn_s_setprio(0);                                         \
        asm volatile("" ::: "memory");          /* pin before barrier */       \
        asm volatile("s_waitcnt vmcnt(" VMSTR ")" ::: "memory");               \
        __builtin_amdgcn_s_barrier();                                          \
    }

    // ---- prologue: stage tiles 0,1 into bufs 0,1; publish tile 0 ----
    stage(0, 0, 0);
    stage(8192, 16384, BK);
    asm volatile("s_waitcnt vmcnt(3)" ::: "memory");   // tile 0 landed
    __builtin_amdgcn_s_barrier();

    // ---- main loop: bodies 0..59 (20 x 3, static offsets) ----
    unsigned int kb = 2 * BK;   // byte offset of tile staged at body 0
    for (int it = 0; it < 20; ++it) {
        BODY(0,     0,     16384, 32768, 1, kb,          "3");  // t=3it+0: rd buf0, st buf2
        BODY(8192,  16384, 0,     0,     1, kb + BK,     "3");  // t=3it+1: rd buf1, st buf0
        BODY(16384, 32768, 8192,  16384, 1, kb + 2 * BK, "3");  // t=3it+2: rd buf2, st buf1
        kb += 3 * BK;
    }

    // ---- tail: bodies 60,61 stage tiles 62,63; body 62 vmcnt(0); body 63 pure ----
    BODY(0,     0,     16384, 32768, 1, (unsigned int)(62 * BK), "3");  // body 60
    BODY(8192,  16384, 0,     0,     1, (unsigned int)(63 * BK), "3");  // body 61
    BODY(16384, 32768, 0,     0,     0, 0u,                      "0");  // body 62
    {   // body 63: reads buf0 (tile 63), MFMA only
        asm volatile("" ::: "memory");
        v4i a_[4], b_[4];
#pragma unroll
        for (int mi = 0; mi < 4; ++mi)
            a_[mi] = *(const v4i*)&sA[0 + rowA + mi * 2048 + colA];
#pragma unroll
        for (int ni = 0; ni < 4; ++ni)
            b_[ni] = *(const v4i*)&sB[0 + rowB + ni * 2048 + colB];
        __builtin_amdgcn_s_setprio(1);
#pragma unroll
        for (int mi = 0; mi < 4; ++mi)
#pragma unroll
            for (int ni = 0; ni < 4; ++ni)
                acc[mi][ni] = __builtin_amdgcn_mfma_i32_16x16x64_i8(
                    a_[mi], b_[ni], acc[mi][ni], 0, 0, 0);
        __builtin_amdgcn_s_setprio(0);
    }
#undef BODY

    // ---- LDS-transpose epilogue: full-cacheline f32x4 NON-TEMPORAL stores ----
    __syncthreads();   // all LDS reads of the K-loop complete before reuse
    float* ws_ = (float*)&smem_[wid * 8704];   // 32 rows x 68 floats per wave

    const int mrow0 = m0 + wm * 64 + ((lane >> 4) << 2);
    const int ncol0 = n0 + wn * 64 + (lane & 15);
    float xsv[4][4], scv[4], bsv[4];
#pragma unroll
    for (int mi = 0; mi < 4; ++mi)
#pragma unroll
        for (int r2 = 0; r2 < 4; ++r2) xsv[mi][r2] = xs[mrow0 + mi * 16 + r2];
#pragma unroll
    for (int ni = 0; ni < 4; ++ni) {
        scv[ni] = scale[ncol0 + ni * 16];
        bsv[ni] = bias[ncol0 + ni * 16];
    }

    const int mbase = m0 + wm * 64;
    const int nbase = n0 + wn * 64;
#pragma unroll
    for (int pass = 0; pass < 2; ++pass) {
#pragma unroll
        for (int mh = 0; mh < 2; ++mh) {
            const int mi = pass * 2 + mh;
#pragma unroll
            for (int ni = 0; ni < 4; ++ni) {
#pragma unroll
                for (int r2 = 0; r2 < 4; ++r2) {
                    const int lrow = mh * 16 + ((lane >> 4) << 2) + r2;
                    ws_[lrow * 68 + ni * 16 + (lane & 15)] =
                        (float)acc[mi][ni][r2] * xsv[mi][r2] * scv[ni] + bsv[ni];
                }
            }
        }
#pragma unroll
        for (int j = 0; j < 8; ++j) {
            const int lrow = j * 4 + (lane >> 4);
            const f32x4 v4 = *(const f32x4*)&ws_[lrow * 68 + (lane & 15) * 4];
            const int m = mbase + pass * 32 + lrow;
            __builtin_nontemporal_store(v4, (f32x4*)&out[(size_t)m * N + nbase + (lane & 15) * 4]);
        }
    }
#undef sA
#undef sB
}

extern "C" void kernel_launch(void* const* d_in, const int* in_sizes, int n_in,
                              void* d_out, int out_size, void* d_ws, size_t ws_size,
                              hipStream_t stream) {
    const float* x     = (const float*)d_in[0];
    const int*   w32   = (const int*)d_in[1];
    const float* scale = (const float*)d_in[2];
    const float* bias  = (const float*)d_in[3];
    float* out = (float*)d_out;

    const int M = in_sizes[0] / K_DIM;   // 8192
    const int N = in_sizes[2];           // 11008

    char* ws = (char*)d_ws;
    signed char* xq = (signed char*)ws;                                  // M*K
    float* xs = (float*)(ws + (size_t)M * K_DIM);                        // M floats
    signed char* w8 = (signed char*)(ws + (size_t)M * K_DIM + (size_t)M * sizeof(float));  // N*K

    quant_kernel<<<M, 256, 0, stream>>>(x, xq, xs);

    const int n16 = (N * K_DIM) / 16;
    repack_kernel<<<(n16 + 255) / 256, 256, 0, stream>>>(w32, (int4*)w8, n16);

    gemm_kernel<<<dim3(N / BN, M / BM), 512, 0, stream>>>(xq, w8, xs, scale, bias, out, N);
}

// Round 23
// 448.213 us; speedup vs baseline: 1.7941x; 1.0222x over previous
//
#include <hip/hip_runtime.h>

typedef int v4i __attribute__((ext_vector_type(4)));
typedef float f32x4 __attribute__((ext_vector_type(4)));

static constexpr int K_DIM = 4096;
static constexpr int BM = 128, BN = 256, BK = 64;

// ---------------- per-token dynamic quantization ----------------
__global__ __launch_bounds__(256) void quant_kernel(const float* __restrict__ x,
                                                    signed char* __restrict__ xq,
                                                    float* __restrict__ xs) {
    const int token = blockIdx.x;
    const float4* row = (const float4*)(x + (size_t)token * K_DIM);
    const int t = threadIdx.x;
    float4 v[4];
    float m = 0.f;
#pragma unroll
    for (int i = 0; i < 4; ++i) {
        v[i] = row[t * 4 + i];
        m = fmaxf(m, fabsf(v[i].x));
        m = fmaxf(m, fabsf(v[i].y));
        m = fmaxf(m, fabsf(v[i].z));
        m = fmaxf(m, fabsf(v[i].w));
    }
#pragma unroll
    for (int d = 32; d > 0; d >>= 1) m = fmaxf(m, __shfl_xor(m, d));
    __shared__ float red[4];
    if ((t & 63) == 0) red[t >> 6] = m;
    __syncthreads();
    const float am = fmaxf(fmaxf(red[0], red[1]), fmaxf(red[2], red[3]));
    const float s = fmaxf(am, 1e-8f) * (1.0f / 127.0f);
    const float inv = 127.0f / fmaxf(am, 1e-8f);

    int pk[4];
#pragma unroll
    for (int i = 0; i < 4; ++i) {
        int q0 = (int)fminf(127.f, fmaxf(-127.f, rintf(v[i].x * inv)));
        int q1 = (int)fminf(127.f, fmaxf(-127.f, rintf(v[i].y * inv)));
        int q2 = (int)fminf(127.f, fmaxf(-127.f, rintf(v[i].z * inv)));
        int q3 = (int)fminf(127.f, fmaxf(-127.f, rintf(v[i].w * inv)));
        pk[i] = (q0 & 255) | ((q1 & 255) << 8) | ((q2 & 255) << 16) | (q3 << 24);
    }
    ((int4*)(xq + (size_t)token * K_DIM))[t] = make_int4(pk[0], pk[1], pk[2], pk[3]);
    if (t == 0) xs[token] = s;
}

// ---------------- weight repack: int32 -> packed int8 ----------------
__global__ __launch_bounds__(256) void repack_kernel(const int* __restrict__ w32,
                                                     int4* __restrict__ w8,
                                                     int n16) {
    const int idx = blockIdx.x * 256 + threadIdx.x;
    if (idx >= n16) return;
    const int4* src = (const int4*)w32 + (size_t)idx * 4;
    int4 a = src[0], b = src[1], c = src[2], d = src[3];
    int p0 = (a.x & 255) | ((a.y & 255) << 8) | ((a.z & 255) << 16) | (a.w << 24);
    int p1 = (b.x & 255) | ((b.y & 255) << 8) | ((b.z & 255) << 16) | (b.w << 24);
    int p2 = (c.x & 255) | ((c.y & 255) << 8) | ((c.z & 255) << 16) | (c.w << 24);
    int p3 = (d.x & 255) | ((d.y & 255) << 8) | ((d.z & 255) << 16) | (d.w << 24);
    w8[idx] = make_int4(p0, p1, p2, p3);
}

// ---- int8 MFMA GEMM: R22 (single-barrier 3-buf rotation, counted vmcnt(3),
// ---- silicon-verified zero-conflict layout, LDS-transpose epilogue, NT
// ---- stores) with GROUP=8: A-slice 4 MB fits a single XCD's L2 ----
__global__ __launch_bounds__(512, 4) void gemm_kernel(const signed char* __restrict__ xq,
                                                      const signed char* __restrict__ w8,
                                                      const float* __restrict__ xs,
                                                      const float* __restrict__ scale,
                                                      const float* __restrict__ bias,
                                                      float* __restrict__ out,
                                                      int N) {
    __shared__ __align__(16) signed char smem_[73728];   // sA 24 KB | sB 48 KB; reused as epilogue scratch
#define sA (smem_)
#define sB (smem_ + 24576)

    const int tid = threadIdx.x;
    const int lane = tid & 63;
    const int wid = tid >> 6;          // 8 waves: 2(M) x 4(N)
    const int wm = wid >> 2;
    const int wn = wid & 3;

    // ---- 2-D supertiled block mapping (GROUP=8 by-rows per group) ----
    // group = 43 bx x 8 by = 344 blocks (344 % 8 == 0 -> bijective XCD swizzle).
    // A slice per group = 8 x 0.5 MB = 4 MB -> fits one XCD L2.
    const int GROUP = 8;
    int flat = blockIdx.y * gridDim.x + blockIdx.x;
    const int gsize = gridDim.x * GROUP;              // 344
    const int group = flat / gsize;
    int r = flat % gsize;
    if ((gsize & 7) == 0) r = (r & 7) * (gsize >> 3) + (r >> 3);
    const int bx = r / GROUP;
    const int by = group * GROUP + (r % GROUP);
    const int m0 = by * BM;
    const int n0 = bx * BN;

    v4i acc[4][4];
    const v4i vzero = {0, 0, 0, 0};
#pragma unroll
    for (int i = 0; i < 4; ++i)
#pragma unroll
        for (int j = 0; j < 4; ++j) acc[i][j] = vzero;

    // ---- staging sources (silicon-verified involution; LDS dest linear) ----
    const int srow = tid >> 3;
    const int s = (tid & 7) ^ (srow & 7);
    const signed char* srcA = xq + ((size_t)m0 + srow + (s >> 2) * 64) * K_DIM + (s & 3) * 16;
    const signed char* srcB = w8 + ((size_t)n0 + srow + (s >> 2) * 128) * K_DIM + (s & 3) * 16;

    auto stage = [&](int offA, int offB, unsigned int kb) {   // 3 issues: A, B-lo, B-hi
        __builtin_amdgcn_global_load_lds(
            (const __attribute__((address_space(1))) void*)(srcA + kb),
            (__attribute__((address_space(3))) void*)&sA[offA + wid * 1024], 16, 0, 0);
        __builtin_amdgcn_global_load_lds(
            (const __attribute__((address_space(1))) void*)(srcB + kb),
            (__attribute__((address_space(3))) void*)&sB[offB + wid * 1024], 16, 0, 0);
        __builtin_amdgcn_global_load_lds(
            (const __attribute__((address_space(1))) void*)(srcB + (size_t)64 * K_DIM + kb),
            (__attribute__((address_space(3))) void*)&sB[offB + 8192 + wid * 1024], 16, 0, 0);
    };

    // ---- read-side per-lane constants (silicon-verified zero-conflict) ----
    const int colA = ((wm * 4 + (lane >> 4)) ^ (lane & 7)) << 4;
    const int colB = (((wn >> 1) * 4 + (lane >> 4)) ^ (lane & 7)) << 4;
    const int rowA = (lane & 15) * 128;
    const int rowB = ((wn & 1) * 64 + (lane & 15)) * 128;

#define BODY(ORa, ORb, OSa, OSb, DOSTAGE, KB, VMSTR)                           \
    {                                                                          \
        asm volatile("" ::: "memory");          /* pin after prev barrier */   \
        if (DOSTAGE) stage((OSa), (OSb), (KB));                                \
        v4i a_[4], b_[4];                                                      \
        _Pragma("unroll") for (int mi = 0; mi < 4; ++mi)                       \
            a_[mi] = *(const v4i*)&sA[(ORa) + rowA + mi * 2048 + colA];        \
        _Pragma("unroll") for (int ni = 0; ni < 4; ++ni)                       \
            b_[ni] = *(const v4i*)&sB[(ORb) + rowB + ni * 2048 + colB];        \
        __builtin_amdgcn_s_setprio(1);                                         \
        _Pragma("unroll") for (int mi = 0; mi < 4; ++mi)                       \
            _Pragma("unroll") for (int ni = 0; ni < 4; ++ni)                   \
                acc[mi][ni] = __builtin_amdgcn_mfma_i32_16x16x64_i8(           \
                    a_[mi], b_[ni], acc[mi][ni], 0, 0, 0);                     \
        __builtin_amdgcn_s_setprio(0);                                         \
        asm volatile("" ::: "memory");          /* pin before barrier */       \
        asm volatile("s_waitcnt vmcnt(" VMSTR ")" ::: "memory");               \
        __builtin_amdgcn_s_barrier();                                          \
    }

    // ---- prologue: stage tiles 0,1 into bufs 0,1; publish tile 0 ----
    stage(0, 0, 0);
    stage(8192, 16384, BK);
    asm volatile("s_waitcnt vmcnt(3)" ::: "memory");   // tile 0 landed
    __builtin_amdgcn_s_barrier();

    // ---- main loop: bodies 0..59 (20 x 3, static offsets) ----
    unsigned int kb = 2 * BK;   // byte offset of tile staged at body 0
    for (int it = 0; it < 20; ++it) {
        BODY(0,     0,     16384, 32768, 1, kb,          "3");  // t=3it+0: rd buf0, st buf2
        BODY(8192,  16384, 0,     0,     1, kb + BK,     "3");  // t=3it+1: rd buf1, st buf0
        BODY(16384, 32768, 8192,  16384, 1, kb + 2 * BK, "3");  // t=3it+2: rd buf2, st buf1
        kb += 3 * BK;
    }

    // ---- tail: bodies 60,61 stage tiles 62,63; body 62 vmcnt(0); body 63 pure ----
    BODY(0,     0,     16384, 32768, 1, (unsigned int)(62 * BK), "3");  // body 60
    BODY(8192,  16384, 0,     0,     1, (unsigned int)(63 * BK), "3");  // body 61
    BODY(16384, 32768, 0,     0,     0, 0u,                      "0");  // body 62
    {   // body 63: reads buf0 (tile 63), MFMA only
        asm volatile("" ::: "memory");
        v4i a_[4], b_[4];
#pragma unroll
        for (int mi = 0; mi < 4; ++mi)
            a_[mi] = *(const v4i*)&sA[0 + rowA + mi * 2048 + colA];
#pragma unroll
        for (int ni = 0; ni < 4; ++ni)
            b_[ni] = *(const v4i*)&sB[0 + rowB + ni * 2048 + colB];
        __builtin_amdgcn_s_setprio(1);
#pragma unroll
        for (int mi = 0; mi < 4; ++mi)
#pragma unroll
            for (int ni = 0; ni < 4; ++ni)
                acc[mi][ni] = __builtin_amdgcn_mfma_i32_16x16x64_i8(
                    a_[mi], b_[ni], acc[mi][ni], 0, 0, 0);
        __builtin_amdgcn_s_setprio(0);
    }
#undef BODY

    // ---- LDS-transpose epilogue: full-cacheline f32x4 NON-TEMPORAL stores ----
    __syncthreads();   // all LDS reads of the K-loop complete before reuse
    float* ws_ = (float*)&smem_[wid * 8704];   // 32 rows x 68 floats per wave

    const int mrow0 = m0 + wm * 64 + ((lane >> 4) << 2);
    const int ncol0 = n0 + wn * 64 + (lane & 15);
    float xsv[4][4], scv[4], bsv[4];
#pragma unroll
    for (int mi = 0; mi < 4; ++mi)
#pragma unroll
        for (int r2 = 0; r2 < 4; ++r2) xsv[mi][r2] = xs[mrow0 + mi * 16 + r2];
#pragma unroll
    for (int ni = 0; ni < 4; ++ni) {
        scv[ni] = scale[ncol0 + ni * 16];
        bsv[ni] = bias[ncol0 + ni * 16];
    }

    const int mbase = m0 + wm * 64;
    const int nbase = n0 + wn * 64;
#pragma unroll
    for (int pass = 0; pass < 2; ++pass) {
#pragma unroll
        for (int mh = 0; mh < 2; ++mh) {
            const int mi = pass * 2 + mh;
#pragma unroll
            for (int ni = 0; ni < 4; ++ni) {
#pragma unroll
                for (int r2 = 0; r2 < 4; ++r2) {
                    const int lrow = mh * 16 + ((lane >> 4) << 2) + r2;
                    ws_[lrow * 68 + ni * 16 + (lane & 15)] =
                        (float)acc[mi][ni][r2] * xsv[mi][r2] * scv[ni] + bsv[ni];
                }
            }
        }
#pragma unroll
        for (int j = 0; j < 8; ++j) {
            const int lrow = j * 4 + (lane >> 4);
            const f32x4 v4 = *(const f32x4*)&ws_[lrow * 68 + (lane & 15) * 4];
            const int m = mbase + pass * 32 + lrow;
            __builtin_nontemporal_store(v4, (f32x4*)&out[(size_t)m * N + nbase + (lane & 15) * 4]);
        }
    }
#undef sA
#undef sB
}

extern "C" void kernel_launch(void* const* d_in, const int* in_sizes, int n_in,
                              void* d_out, int out_size, void* d_ws, size_t ws_size,
                              hipStream_t stream) {
    const float* x     = (const float*)d_in[0];
    const int*   w32   = (const int*)d_in[1];
    const float* scale = (const float*)d_in[2];
    const float* bias  = (const float*)d_in[3];
    float* out = (float*)d_out;

    const int M = in_sizes[0] / K_DIM;   // 8192
    const int N = in_sizes[2];           // 11008

    char* ws = (char*)d_ws;
    signed char* xq = (signed char*)ws;                                  // M*K
    float* xs = (float*)(ws + (size_t)M * K_DIM);                        // M floats
    signed char* w8 = (signed char*)(ws + (size_t)M * K_DIM + (size_t)M * sizeof(float));  // N*K

    quant_kernel<<<M, 256, 0, stream>>>(x, xq, xs);

    const int n16 = (N * K_DIM) / 16;
    repack_kernel<<<(n16 + 255) / 256, 256, 0, stream>>>(w32, (int4*)w8, n16);

    gemm_kernel<<<dim3(N / BN, M / BM), 512, 0, stream>>>(xq, w8, xs, scale, bias, out, N);
}